// Round 7
// baseline (219.074 us; speedup 1.0000x reference)
//
#include <hip/hip_runtime.h>
#include <math.h>

#define EPS_F 1e-6f

typedef __attribute__((ext_vector_type(8))) short short8;
typedef __attribute__((ext_vector_type(4))) float f32x4;
typedef unsigned long long ull;

static __device__ __forceinline__ unsigned short f2bf(float f) {
    unsigned u = __float_as_uint(f);
    u += 0x7fff + ((u >> 16) & 1);          // round-to-nearest-even
    return (unsigned short)(u >> 16);
}
static __device__ __forceinline__ ull pack4(float a, float b, float c, float d) {
    return (ull)f2bf(a) | ((ull)f2bf(b) << 16) | ((ull)f2bf(c) << 32) | ((ull)f2bf(d) << 48);
}
static __device__ __forceinline__ float bf2f(unsigned short s) {
    return __uint_as_float(((unsigned)s) << 16);
}

// ---------------- small kernels ----------------

__global__ void kff(const float* __restrict__ F, float* __restrict__ FF) {
    int i = blockIdx.x, j = threadIdx.x;
    float s = 0.f;
    for (int k = 0; k < 128; ++k) s += F[k*128 + i] * F[k*128 + j];
    FF[i*128 + j] = s;
}

__global__ void knorm(const float* __restrict__ FF, float* __restrict__ inv) {
    float s = 0.f;
    for (int idx = threadIdx.x; idx < 128*128; idx += 256) { float v = FF[idx]; s += v*v; }
    for (int o = 32; o > 0; o >>= 1) s += __shfl_down(s, o);
    __shared__ float wsum[4];
    int lane = threadIdx.x & 63, w = threadIdx.x >> 6;
    if (lane == 0) wsum[w] = s;
    __syncthreads();
    if (threadIdx.x == 0) inv[0] = 1.f / (sqrtf(wsum[0]+wsum[1]+wsum[2]+wsum[3]) + EPS_F);
}

// X (f32, 1M elems) -> bf16
__global__ void kxbf(const float* __restrict__ X, short* __restrict__ Xb) {
    int i = blockIdx.x*blockDim.x + threadIdx.x;    // group of 8
    const float4* p = (const float4*)(X + (size_t)i*8);
    float4 v0 = p[0], v1 = p[1];
    *(ull*)&Xb[(size_t)i*8    ] = pack4(v0.x, v0.y, v0.z, v0.w);
    *(ull*)&Xb[(size_t)i*8 + 4] = pack4(v1.x, v1.y, v1.z, v1.w);
}

// ---------------- 3-stage pipelined split-K GEMM ----------------
// C_part[split][128][8192] = Ab[128][K](bf16) * op(B),
//   op(B)[k][n] = TRANSB ? Qg[n][k] : Qg[k][n]
// BM=128, BN=64, BK=32, 256 thr (4 waves 2m x 2n).
// 3 LDS buffers, 2 register sets, loads issued 2 tiles ahead:
//   iter ks: load(tile ks+2) ; MFMA(buf ks%3) ; ds_write(buf (ks+1)%3 <- regs ks+1) ; barrier
// The ds_write's vmcnt wait targets loads issued one full iteration earlier.
template<bool TRANSB>
__global__ __launch_bounds__(256) void gemm_p3(
    const short* __restrict__ Ab, const float* __restrict__ Qg,
    float* __restrict__ Cp, int N, int K, int KC)
{
    constexpr int LDT = 40;                 // shorts/row: 32 data + 8 pad (80 B)
    constexpr int ASZ = 128 * LDT;
    constexpr int BSZ = 64 * LDT;
    __shared__ short As[3 * ASZ];
    __shared__ short Bs[3 * BSZ];

    const int t    = threadIdx.x;
    const int lane = t & 63;
    const int w    = t >> 6;
    const int wm   = (w >> 1) * 64;
    const int wn   = (w & 1)  * 32;
    const int l16  = lane & 15;
    const int lq   = lane >> 4;
    const int n0   = blockIdx.x * 64;
    const int kb   = blockIdx.y * KC;
    const int NS   = KC >> 5;               // tiles (even: 16 or 32)

    float* Cout = Cp + (size_t)blockIdx.y * (128 * 8192);

    // staging decomposition
    const int ar0 = t >> 2, ako = (t & 3) * 8;      // A: rows ar0, ar0+64
    const int br0 = t >> 3, bko = (t & 7) * 4;      // B copy: rows br0, br0+32
    const int bn  = t & 63, bkh = t >> 6;           // B transpose: col bn, k-octet

    f32x4 acc[4][2];
    #pragma unroll
    for (int i = 0; i < 4; ++i) { acc[i][0] = (f32x4){0,0,0,0}; acc[i][1] = (f32x4){0,0,0,0}; }

    // two register sets (static names — no runtime reg-array indexing)
    short8 saA0, saA1, saB0, saB1;
    float4 sbA0, sbA1, sbB0, sbB1;
    float  sbtA[8], sbtB[8];

#define LOAD_T(k0, SA0, SA1, SB0, SB1, SBT) do {                                  \
        SA0 = *(const short8*)&Ab[(size_t)ar0*K + (k0) + ako];                    \
        SA1 = *(const short8*)&Ab[(size_t)(ar0+64)*K + (k0) + ako];               \
        if constexpr (TRANSB) {                                                   \
            SB0 = *(const float4*)&Qg[(size_t)(n0+br0   )*K + (k0) + bko];        \
            SB1 = *(const float4*)&Qg[(size_t)(n0+br0+32)*K + (k0) + bko];        \
        } else {                                                                  \
            _Pragma("unroll")                                                     \
            for (int j = 0; j < 8; ++j)                                           \
                SBT[j] = Qg[(size_t)((k0) + bkh*8 + j)*N + n0 + bn];              \
        }                                                                         \
    } while (0)

#define WRITE_T(buf, SA0, SA1, SB0, SB1, SBT) do {                                \
        short* asb = &As[(buf)*ASZ];                                              \
        short* bsb = &Bs[(buf)*BSZ];                                              \
        *(short8*)&asb[ar0*LDT + ako]      = SA0;                                 \
        *(short8*)&asb[(ar0+64)*LDT + ako] = SA1;                                 \
        if constexpr (TRANSB) {                                                   \
            *(ull*)&bsb[br0*LDT + bko]      = pack4(SB0.x, SB0.y, SB0.z, SB0.w);  \
            *(ull*)&bsb[(br0+32)*LDT + bko] = pack4(SB1.x, SB1.y, SB1.z, SB1.w);  \
        } else {                                                                  \
            short8 p;                                                             \
            _Pragma("unroll")                                                     \
            for (int j = 0; j < 8; ++j) p[j] = (short)f2bf(SBT[j]);               \
            *(short8*)&bsb[bn*LDT + bkh*8] = p;                                   \
        }                                                                         \
    } while (0)

#define MFMA_T(buf) do {                                                          \
        const short* asb = &As[(buf)*ASZ];                                        \
        const short* bsb = &Bs[(buf)*BSZ];                                        \
        short8 af[4], bfr[2];                                                     \
        _Pragma("unroll")                                                         \
        for (int mt = 0; mt < 4; ++mt)                                            \
            af[mt] = *(const short8*)&asb[(wm + mt*16 + l16)*LDT + lq*8];         \
        bfr[0] = *(const short8*)&bsb[(wn      + l16)*LDT + lq*8];                \
        bfr[1] = *(const short8*)&bsb[(wn + 16 + l16)*LDT + lq*8];                \
        _Pragma("unroll")                                                         \
        for (int mt = 0; mt < 4; ++mt) {                                          \
            acc[mt][0] = __builtin_amdgcn_mfma_f32_16x16x32_bf16(af[mt], bfr[0], acc[mt][0], 0, 0, 0); \
            acc[mt][1] = __builtin_amdgcn_mfma_f32_16x16x32_bf16(af[mt], bfr[1], acc[mt][1], 0, 0, 0); \
        }                                                                         \
    } while (0)

    // ---- prologue: tile0 -> setA -> LDS buf0; tile1 -> setB (in flight)
    LOAD_T(kb,      saA0, saA1, sbA0, sbA1, sbtA);
    LOAD_T(kb + 32, saB0, saB1, sbB0, sbB1, sbtB);
    WRITE_T(0, saA0, saA1, sbA0, sbA1, sbtA);
    __syncthreads();

    int b0 = 0, b1 = 1, b2 = 2;
    for (int ks = 0; ks < NS; ks += 2) {
        // ---- iteration ks (even): tile ks in buf b0, setB holds tile ks+1
        if (ks + 2 < NS) LOAD_T(kb + (ks+2)*32, saA0, saA1, sbA0, sbA1, sbtA);
        MFMA_T(b0);
        if (ks + 1 < NS) WRITE_T(b1, saB0, saB1, sbB0, sbB1, sbtB);
        __syncthreads();

        // ---- iteration ks+1 (odd): tile ks+1 in buf b1, setA holds tile ks+2
        if (ks + 3 < NS) LOAD_T(kb + (ks+3)*32, saB0, saB1, sbB0, sbB1, sbtB);
        MFMA_T(b1);
        if (ks + 2 < NS) WRITE_T(b2, saA0, saA1, sbA0, sbA1, sbtA);
        __syncthreads();

        int tb = b0; b0 = b2; b2 = b1; b1 = tb;     // rotate by 2
    }

#undef LOAD_T
#undef WRITE_T
#undef MFMA_T

    // ---- epilogue: non-atomic partial store
    #pragma unroll
    for (int mt = 0; mt < 4; ++mt)
        #pragma unroll
        for (int nt = 0; nt < 2; ++nt)
            #pragma unroll
            for (int r = 0; r < 4; ++r)
                Cout[(size_t)(wm + mt*16 + lq*4 + r)*N + n0 + wn + nt*16 + l16] = acc[mt][nt][r];
}

// ---------------- fused Horner (reduces GEMM1 partials, emits bf16 R k-major) ---------
__global__ __launch_bounds__(512) void horner_fused(
    const float* __restrict__ FF, const float* __restrict__ invn,
    const float* __restrict__ lam, const float* __restrict__ gam,
    const float* __restrict__ Yp, short* __restrict__ Rg, int N)
{
    constexpr int LDT = 136;
    constexpr int T = 14;
    constexpr int SPL = 16;
    __shared__ short Abf[128 * LDT];        // [m][k]
    __shared__ short Rs[32 * LDT];          // [j_local][m]

    const int t    = threadIdx.x;
    const int lane = t & 63;
    const int w    = t >> 6;
    const int wm   = (w >> 1) * 32;
    const int wn   = (w & 1) * 16;
    const int l16  = lane & 15;
    const int lq   = lane >> 4;
    const int j0   = blockIdx.x * 32;

    #pragma unroll
    for (int i = 0; i < 8; ++i) {
        int flat = t + i*512;
        int m = flat >> 5, k4 = flat & 31;
        float4 v = *(const float4*)&FF[m*128 + k4*4];
        *(ull*)&Abf[m*LDT + k4*4] = pack4(v.x, v.y, v.z, v.w);
    }
    {
        int j = t & 31, mg = t >> 5;
        float vv[8];
        #pragma unroll
        for (int r2 = 0; r2 < 8; ++r2) {
            size_t idx = (size_t)(mg*8 + r2)*N + j0 + j;
            float s = 0.f;
            #pragma unroll
            for (int sp = 0; sp < SPL; ++sp) s += Yp[(size_t)sp*(128*8192) + idx];
            vv[r2] = s;
        }
        *(ull*)&Rs[j*LDT + mg*8    ] = pack4(vv[0], vv[1], vv[2], vv[3]);
        *(ull*)&Rs[j*LDT + mg*8 + 4] = pack4(vv[4], vv[5], vv[6], vv[7]);
    }
    __syncthreads();

    const int col = j0 + wn + l16;
    float yreg[2][4];
    #pragma unroll
    for (int mt = 0; mt < 2; ++mt)
        #pragma unroll
        for (int r = 0; r < 4; ++r)
            yreg[mt][r] = bf2f((unsigned short)Rs[(wn + l16)*LDT + wm + mt*16 + lq*4 + r]);
    const float s = gam[0] * lam[col] * invn[0];

    for (int it = 0; it < T; ++it) {
        f32x4 racc[2];
        racc[0] = (f32x4){0,0,0,0};
        racc[1] = (f32x4){0,0,0,0};
        #pragma unroll
        for (int kq = 0; kq < 4; ++kq) {
            short8 b  = *(const short8*)&Rs[(wn + l16)*LDT + kq*32 + lq*8];
            short8 a0 = *(const short8*)&Abf[(wm      + l16)*LDT + kq*32 + lq*8];
            short8 a1 = *(const short8*)&Abf[(wm + 16 + l16)*LDT + kq*32 + lq*8];
            racc[0] = __builtin_amdgcn_mfma_f32_16x16x32_bf16(a0, b, racc[0], 0, 0, 0);
            racc[1] = __builtin_amdgcn_mfma_f32_16x16x32_bf16(a1, b, racc[1], 0, 0, 0);
        }
        __syncthreads();
        #pragma unroll
        for (int mt = 0; mt < 2; ++mt) {
            float r0 = yreg[mt][0] + s*racc[mt][0];
            float r1 = yreg[mt][1] + s*racc[mt][1];
            float r2 = yreg[mt][2] + s*racc[mt][2];
            float r3 = yreg[mt][3] + s*racc[mt][3];
            if (it < T-1) {
                *(ull*)&Rs[(wn + l16)*LDT + wm + mt*16 + lq*4] = pack4(r0, r1, r2, r3);
            } else {
                int row = wm + mt*16 + lq*4;
                Rg[(size_t)(row+0)*N + col] = (short)f2bf(r0);
                Rg[(size_t)(row+1)*N + col] = (short)f2bf(r1);
                Rg[(size_t)(row+2)*N + col] = (short)f2bf(r2);
                Rg[(size_t)(row+3)*N + col] = (short)f2bf(r3);
            }
        }
        if (it < T-1) __syncthreads();
    }
}

// ---------------- Z = sum of 8 split partials ----------------
__global__ __launch_bounds__(256) void zred(const float* __restrict__ Zp,
                                            float* __restrict__ Z) {
    int i = (blockIdx.x*blockDim.x + threadIdx.x) * 4;
    f32x4 s = (f32x4){0,0,0,0};
    #pragma unroll
    for (int sp = 0; sp < 8; ++sp) {
        const float4 v = *(const float4*)&Zp[(size_t)sp*(128*8192) + i];
        s[0] += v.x; s[1] += v.y; s[2] += v.z; s[3] += v.w;
    }
    *(f32x4*)&Z[i] = s;
}

// ---------------- launch ----------------

extern "C" void kernel_launch(void* const* d_in, const int* in_sizes, int n_in,
                              void* d_out, int out_size, void* d_ws, size_t ws_size,
                              hipStream_t stream) {
    const float* X   = (const float*)d_in[0];   // 128 x 8192
    const float* F   = (const float*)d_in[1];   // 128 x 128
    const float* Q   = (const float*)d_in[2];   // 8192 x 8192
    const float* lam = (const float*)d_in[3];   // 8192
    const float* gam = (const float*)d_in[4];   // 1
    float* Z = (float*)d_out;                   // 128 x 8192 (f32)

    const int N = 8192, K = 8192;

    char* ws = (char*)d_ws;
    float* FF  = (float*)(ws);                               // 64 KB
    float* inv = (float*)(ws + 65536);                       // 4 B
    short* Xb  = (short*)(ws + 131072);                      // 2 MB
    short* Rg  = (short*)(ws + 2228224);                     // 2 MB
    float* Yp  = (float*)(ws + 4325376);                     // 16 x 4 MB
    float* Zp  = (float*)(ws + 4325376 + 67108864);          // 8 x 4 MB

    hipLaunchKernelGGL(kff,   dim3(128), dim3(128), 0, stream, F, FF);
    hipLaunchKernelGGL(knorm, dim3(1),   dim3(256), 0, stream, FF, inv);
    hipLaunchKernelGGL(kxbf,  dim3(512), dim3(256), 0, stream, X, Xb);

    // GEMM1: Yp[s] = Xb @ Q   (3-stage pipeline, split-K=16, no atomics)
    hipLaunchKernelGGL((gemm_p3<false>), dim3(128, 16), dim3(256), 0, stream,
                       Xb, Q, Yp, N, K, 512);

    // fused Horner: reduce 16 partials, Neumann series, emit bf16 R (k-major)
    hipLaunchKernelGGL(horner_fused, dim3(256), dim3(512), 0, stream,
                       FF, inv, lam, gam, Yp, Rg, N);

    // GEMM2: Zp[s] = Rg @ Q^T  (3-stage pipeline, split-K=8)
    hipLaunchKernelGGL((gemm_p3<true>), dim3(128, 8), dim3(256), 0, stream,
                       Rg, Q, Zp, N, K, 1024);

    // Z = sum_s Zp[s]
    hipLaunchKernelGGL(zred, dim3(1024), dim3(256), 0, stream, Zp, Z);
}

// Round 8
// 205.758 us; speedup vs baseline: 1.0647x; 1.0647x over previous
//
#include <hip/hip_runtime.h>
#include <math.h>

#define EPS_F 1e-6f

typedef __attribute__((ext_vector_type(8))) short short8;
typedef __attribute__((ext_vector_type(4))) float f32x4;
typedef unsigned long long ull;

static __device__ __forceinline__ unsigned short f2bf(float f) {
    unsigned u = __float_as_uint(f);
    u += 0x7fff + ((u >> 16) & 1);          // round-to-nearest-even
    return (unsigned short)(u >> 16);
}
static __device__ __forceinline__ ull pack4(float a, float b, float c, float d) {
    return (ull)f2bf(a) | ((ull)f2bf(b) << 16) | ((ull)f2bf(c) << 32) | ((ull)f2bf(d) << 48);
}
static __device__ __forceinline__ float bf2f(unsigned short s) {
    return __uint_as_float(((unsigned)s) << 16);
}

// raw barrier: publish this wave's LDS ops, sync, and pin scheduling.
// Deliberately NO vmcnt drain — global loads stay in flight across it.
#define BAR() do {                                            \
        asm volatile("s_waitcnt lgkmcnt(0)" ::: "memory");    \
        __builtin_amdgcn_s_barrier();                         \
        __builtin_amdgcn_sched_barrier(0);                    \
    } while (0)

// ---------------- small kernels ----------------

__global__ void kff(const float* __restrict__ F, float* __restrict__ FF) {
    int i = blockIdx.x, j = threadIdx.x;
    float s = 0.f;
    for (int k = 0; k < 128; ++k) s += F[k*128 + i] * F[k*128 + j];
    FF[i*128 + j] = s;
}

__global__ void knorm(const float* __restrict__ FF, float* __restrict__ inv) {
    float s = 0.f;
    for (int idx = threadIdx.x; idx < 128*128; idx += 256) { float v = FF[idx]; s += v*v; }
    for (int o = 32; o > 0; o >>= 1) s += __shfl_down(s, o);
    __shared__ float wsum[4];
    int lane = threadIdx.x & 63, w = threadIdx.x >> 6;
    if (lane == 0) wsum[w] = s;
    __syncthreads();
    if (threadIdx.x == 0) inv[0] = 1.f / (sqrtf(wsum[0]+wsum[1]+wsum[2]+wsum[3]) + EPS_F);
}

// X (f32, 1M elems) -> bf16
__global__ void kxbf(const float* __restrict__ X, short* __restrict__ Xb) {
    int i = blockIdx.x*blockDim.x + threadIdx.x;    // group of 8
    const float4* p = (const float4*)(X + (size_t)i*8);
    float4 v0 = p[0], v1 = p[1];
    *(ull*)&Xb[(size_t)i*8    ] = pack4(v0.x, v0.y, v0.z, v0.w);
    *(ull*)&Xb[(size_t)i*8 + 4] = pack4(v1.x, v1.y, v1.z, v1.w);
}

// ---------------- pipelined split-K GEMM (raw barriers, loads 2 tiles ahead) ----------
// C_part[split][128][8192] = Ab[128][K](bf16) * op(B),
//   op(B)[k][n] = TRANSB ? Qg[n][k] : Qg[k][n]
// BM=128, BN=64, BK=32, 256 thr (4 waves 2m x 2n), split-K=8, non-atomic partials.
// Iter t: issue loads(t+2) ; MFMA buf[t&1] ; ds_write buf[(t+1)&1] (regs loaded at t-1);
//         lgkmcnt(0) ; raw s_barrier.  No vmcnt(0) anywhere in the loop.
template<bool TRANSB>
__global__ __launch_bounds__(256) void gemm_pipe(
    const short* __restrict__ Ab, const float* __restrict__ Qg,
    float* __restrict__ Cp, int N, int K, int KC)
{
    constexpr int LDT = 40;                 // shorts/row: 32 data + 8 pad (80 B)
    constexpr int ASZ = 128 * LDT;
    constexpr int BSZ = 64 * LDT;
    __shared__ short As[2][ASZ];
    __shared__ short Bs[2][BSZ];

    const int t    = threadIdx.x;
    const int lane = t & 63;
    const int w    = t >> 6;
    const int wm   = (w >> 1) * 64;
    const int wn   = (w & 1)  * 32;
    const int l16  = lane & 15;
    const int lq   = lane >> 4;
    const int n0   = blockIdx.x * 64;
    const int kb   = blockIdx.y * KC;
    const int NS   = KC >> 5;               // 32 tiles (even)

    float* Cout = Cp + (size_t)blockIdx.y * (128 * 8192);

    // staging decomposition
    const int ar0 = t >> 2, ako = (t & 3) * 8;      // A: rows ar0, ar0+64
    const int br0 = t >> 3, bko = (t & 7) * 4;      // B copy: rows br0, br0+32
    const int bn  = t & 63, bkh = t >> 6;           // B transpose: col bn, k-octet

    f32x4 acc[4][2];
    #pragma unroll
    for (int i = 0; i < 4; ++i) { acc[i][0] = (f32x4){0,0,0,0}; acc[i][1] = (f32x4){0,0,0,0}; }

    // two register sets (static names)
    short8 saA0, saA1, saB0, saB1;
    float4 sbA0, sbA1, sbB0, sbB1;
    float  sbtA[8], sbtB[8];

#define LOAD_T(k0, SA0, SA1, SB0, SB1, SBT) do {                                  \
        SA0 = *(const short8*)&Ab[(size_t)ar0*K + (k0) + ako];                    \
        SA1 = *(const short8*)&Ab[(size_t)(ar0+64)*K + (k0) + ako];               \
        if constexpr (TRANSB) {                                                   \
            SB0 = *(const float4*)&Qg[(size_t)(n0+br0   )*K + (k0) + bko];        \
            SB1 = *(const float4*)&Qg[(size_t)(n0+br0+32)*K + (k0) + bko];        \
        } else {                                                                  \
            _Pragma("unroll")                                                     \
            for (int j = 0; j < 8; ++j)                                           \
                SBT[j] = Qg[(size_t)((k0) + bkh*8 + j)*N + n0 + bn];              \
        }                                                                         \
    } while (0)

#define WRITE_T(buf, SA0, SA1, SB0, SB1, SBT) do {                                \
        *(short8*)&As[buf][ar0*LDT + ako]      = SA0;                             \
        *(short8*)&As[buf][(ar0+64)*LDT + ako] = SA1;                             \
        if constexpr (TRANSB) {                                                   \
            *(ull*)&Bs[buf][br0*LDT + bko]      = pack4(SB0.x, SB0.y, SB0.z, SB0.w); \
            *(ull*)&Bs[buf][(br0+32)*LDT + bko] = pack4(SB1.x, SB1.y, SB1.z, SB1.w); \
        } else {                                                                  \
            short8 p;                                                             \
            _Pragma("unroll")                                                     \
            for (int j = 0; j < 8; ++j) p[j] = (short)f2bf(SBT[j]);               \
            *(short8*)&Bs[buf][bn*LDT + bkh*8] = p;                               \
        }                                                                         \
    } while (0)

#define MFMA_T(buf) do {                                                          \
        short8 af[4], bfr[2];                                                     \
        _Pragma("unroll")                                                         \
        for (int mt = 0; mt < 4; ++mt)                                            \
            af[mt] = *(const short8*)&As[buf][(wm + mt*16 + l16)*LDT + lq*8];     \
        bfr[0] = *(const short8*)&Bs[buf][(wn      + l16)*LDT + lq*8];            \
        bfr[1] = *(const short8*)&Bs[buf][(wn + 16 + l16)*LDT + lq*8];            \
        _Pragma("unroll")                                                         \
        for (int mt = 0; mt < 4; ++mt) {                                          \
            acc[mt][0] = __builtin_amdgcn_mfma_f32_16x16x32_bf16(af[mt], bfr[0], acc[mt][0], 0, 0, 0); \
            acc[mt][1] = __builtin_amdgcn_mfma_f32_16x16x32_bf16(af[mt], bfr[1], acc[mt][1], 0, 0, 0); \
        }                                                                         \
    } while (0)

    // ---- prologue: tile0 -> setA -> buf0; tile1 -> setB (left in flight)
    LOAD_T(kb,      saA0, saA1, sbA0, sbA1, sbtA);
    LOAD_T(kb + 32, saB0, saB1, sbB0, sbB1, sbtB);
    WRITE_T(0, saA0, saA1, sbA0, sbA1, sbtA);   // compiler waits only setA's loads
    BAR();

    for (int ks = 0; ks < NS; ks += 2) {
        // ---- iter ks (even): compute buf0 (tile ks); setB holds tile ks+1
        if (ks + 2 < NS) LOAD_T(kb + (ks+2)*32, saA0, saA1, sbA0, sbA1, sbtA);
        MFMA_T(0);
        if (ks + 1 < NS) WRITE_T(1, saB0, saB1, sbB0, sbB1, sbtB);
        BAR();

        // ---- iter ks+1 (odd): compute buf1 (tile ks+1); setA holds tile ks+2
        if (ks + 3 < NS) LOAD_T(kb + (ks+3)*32, saB0, saB1, sbB0, sbB1, sbtB);
        MFMA_T(1);
        if (ks + 2 < NS) WRITE_T(0, saA0, saA1, sbA0, sbA1, sbtA);
        BAR();
    }

#undef LOAD_T
#undef WRITE_T
#undef MFMA_T

    // ---- epilogue: non-atomic partial store
    #pragma unroll
    for (int mt = 0; mt < 4; ++mt)
        #pragma unroll
        for (int nt = 0; nt < 2; ++nt)
            #pragma unroll
            for (int r = 0; r < 4; ++r)
                Cout[(size_t)(wm + mt*16 + lq*4 + r)*N + n0 + wn + nt*16 + l16] = acc[mt][nt][r];
}

// ---------------- fused Horner (reduces GEMM1 partials, emits bf16 R k-major) ---------
__global__ __launch_bounds__(512) void horner_fused(
    const float* __restrict__ FF, const float* __restrict__ invn,
    const float* __restrict__ lam, const float* __restrict__ gam,
    const float* __restrict__ Yp, short* __restrict__ Rg, int N)
{
    constexpr int LDT = 136;
    constexpr int T = 14;
    constexpr int SPL = 8;
    __shared__ short Abf[128 * LDT];        // [m][k]
    __shared__ short Rs[32 * LDT];          // [j_local][m]

    const int t    = threadIdx.x;
    const int lane = t & 63;
    const int w    = t >> 6;
    const int wm   = (w >> 1) * 32;
    const int wn   = (w & 1) * 16;
    const int l16  = lane & 15;
    const int lq   = lane >> 4;
    const int j0   = blockIdx.x * 32;

    #pragma unroll
    for (int i = 0; i < 8; ++i) {
        int flat = t + i*512;
        int m = flat >> 5, k4 = flat & 31;
        float4 v = *(const float4*)&FF[m*128 + k4*4];
        *(ull*)&Abf[m*LDT + k4*4] = pack4(v.x, v.y, v.z, v.w);
    }
    {
        int j = t & 31, mg = t >> 5;
        float vv[8];
        #pragma unroll
        for (int r2 = 0; r2 < 8; ++r2) {
            size_t idx = (size_t)(mg*8 + r2)*N + j0 + j;
            float s = 0.f;
            #pragma unroll
            for (int sp = 0; sp < SPL; ++sp) s += Yp[(size_t)sp*(128*8192) + idx];
            vv[r2] = s;
        }
        *(ull*)&Rs[j*LDT + mg*8    ] = pack4(vv[0], vv[1], vv[2], vv[3]);
        *(ull*)&Rs[j*LDT + mg*8 + 4] = pack4(vv[4], vv[5], vv[6], vv[7]);
    }
    __syncthreads();

    const int col = j0 + wn + l16;
    float yreg[2][4];
    #pragma unroll
    for (int mt = 0; mt < 2; ++mt)
        #pragma unroll
        for (int r = 0; r < 4; ++r)
            yreg[mt][r] = bf2f((unsigned short)Rs[(wn + l16)*LDT + wm + mt*16 + lq*4 + r]);
    const float s = gam[0] * lam[col] * invn[0];

    for (int it = 0; it < T; ++it) {
        f32x4 racc[2];
        racc[0] = (f32x4){0,0,0,0};
        racc[1] = (f32x4){0,0,0,0};
        #pragma unroll
        for (int kq = 0; kq < 4; ++kq) {
            short8 b  = *(const short8*)&Rs[(wn + l16)*LDT + kq*32 + lq*8];
            short8 a0 = *(const short8*)&Abf[(wm      + l16)*LDT + kq*32 + lq*8];
            short8 a1 = *(const short8*)&Abf[(wm + 16 + l16)*LDT + kq*32 + lq*8];
            racc[0] = __builtin_amdgcn_mfma_f32_16x16x32_bf16(a0, b, racc[0], 0, 0, 0);
            racc[1] = __builtin_amdgcn_mfma_f32_16x16x32_bf16(a1, b, racc[1], 0, 0, 0);
        }
        __syncthreads();
        #pragma unroll
        for (int mt = 0; mt < 2; ++mt) {
            float r0 = yreg[mt][0] + s*racc[mt][0];
            float r1 = yreg[mt][1] + s*racc[mt][1];
            float r2 = yreg[mt][2] + s*racc[mt][2];
            float r3 = yreg[mt][3] + s*racc[mt][3];
            if (it < T-1) {
                *(ull*)&Rs[(wn + l16)*LDT + wm + mt*16 + lq*4] = pack4(r0, r1, r2, r3);
            } else {
                int row = wm + mt*16 + lq*4;
                Rg[(size_t)(row+0)*N + col] = (short)f2bf(r0);
                Rg[(size_t)(row+1)*N + col] = (short)f2bf(r1);
                Rg[(size_t)(row+2)*N + col] = (short)f2bf(r2);
                Rg[(size_t)(row+3)*N + col] = (short)f2bf(r3);
            }
        }
        if (it < T-1) __syncthreads();
    }
}

// ---------------- Z = sum of 8 split partials ----------------
__global__ __launch_bounds__(256) void zred(const float* __restrict__ Zp,
                                            float* __restrict__ Z) {
    int i = (blockIdx.x*blockDim.x + threadIdx.x) * 4;
    f32x4 s = (f32x4){0,0,0,0};
    #pragma unroll
    for (int sp = 0; sp < 8; ++sp) {
        const float4 v = *(const float4*)&Zp[(size_t)sp*(128*8192) + i];
        s[0] += v.x; s[1] += v.y; s[2] += v.z; s[3] += v.w;
    }
    *(f32x4*)&Z[i] = s;
}

// ---------------- launch ----------------

extern "C" void kernel_launch(void* const* d_in, const int* in_sizes, int n_in,
                              void* d_out, int out_size, void* d_ws, size_t ws_size,
                              hipStream_t stream) {
    const float* X   = (const float*)d_in[0];   // 128 x 8192
    const float* F   = (const float*)d_in[1];   // 128 x 128
    const float* Q   = (const float*)d_in[2];   // 8192 x 8192
    const float* lam = (const float*)d_in[3];   // 8192
    const float* gam = (const float*)d_in[4];   // 1
    float* Z = (float*)d_out;                   // 128 x 8192 (f32)

    const int N = 8192, K = 8192;

    char* ws = (char*)d_ws;
    float* FF  = (float*)(ws);                               // 64 KB
    float* inv = (float*)(ws + 65536);                       // 4 B
    short* Xb  = (short*)(ws + 131072);                      // 2 MB
    short* Rg  = (short*)(ws + 2228224);                     // 2 MB
    float* Yp  = (float*)(ws + 4325376);                     // 8 x 4 MB
    float* Zp  = (float*)(ws + 4325376 + 33554432);          // 8 x 4 MB

    hipLaunchKernelGGL(kff,   dim3(128), dim3(128), 0, stream, F, FF);
    hipLaunchKernelGGL(knorm, dim3(1),   dim3(256), 0, stream, FF, inv);
    hipLaunchKernelGGL(kxbf,  dim3(512), dim3(256), 0, stream, X, Xb);

    // GEMM1: Yp[s] = Xb @ Q   (raw-barrier pipeline, split-K=8, no atomics)
    hipLaunchKernelGGL((gemm_pipe<false>), dim3(128, 8), dim3(256), 0, stream,
                       Xb, Q, Yp, N, K, 1024);

    // fused Horner: reduce 8 partials, Neumann series, emit bf16 R (k-major)
    hipLaunchKernelGGL(horner_fused, dim3(256), dim3(512), 0, stream,
                       FF, inv, lam, gam, Yp, Rg, N);

    // GEMM2: Zp[s] = Rg @ Q^T  (raw-barrier pipeline, split-K=8)
    hipLaunchKernelGGL((gemm_pipe<true>), dim3(128, 8), dim3(256), 0, stream,
                       Rg, Q, Zp, N, K, 1024);

    // Z = sum_s Zp[s]
    hipLaunchKernelGGL(zred, dim3(1024), dim3(256), 0, stream, Zp, Z);
}

// Round 9
// 190.574 us; speedup vs baseline: 1.1496x; 1.0797x over previous
//
#include <hip/hip_runtime.h>
#include <math.h>

#define EPS_F 1e-6f

typedef __attribute__((ext_vector_type(8))) short short8;
typedef __attribute__((ext_vector_type(4))) float f32x4;
typedef unsigned long long ull;

static __device__ __forceinline__ unsigned short f2bf(float f) {
    unsigned u = __float_as_uint(f);
    u += 0x7fff + ((u >> 16) & 1);          // round-to-nearest-even
    return (unsigned short)(u >> 16);
}
static __device__ __forceinline__ ull pack4(float a, float b, float c, float d) {
    return (ull)f2bf(a) | ((ull)f2bf(b) << 16) | ((ull)f2bf(c) << 32) | ((ull)f2bf(d) << 48);
}
static __device__ __forceinline__ float bf2f(unsigned short s) {
    return __uint_as_float(((unsigned)s) << 16);
}

// ---------------- small kernels ----------------

__global__ void kff(const float* __restrict__ F, float* __restrict__ FF) {
    int i = blockIdx.x, j = threadIdx.x;
    float s = 0.f;
    for (int k = 0; k < 128; ++k) s += F[k*128 + i] * F[k*128 + j];
    FF[i*128 + j] = s;
}

__global__ void knorm(const float* __restrict__ FF, float* __restrict__ inv) {
    float s = 0.f;
    for (int idx = threadIdx.x; idx < 128*128; idx += 256) { float v = FF[idx]; s += v*v; }
    for (int o = 32; o > 0; o >>= 1) s += __shfl_down(s, o);
    __shared__ float wsum[4];
    int lane = threadIdx.x & 63, w = threadIdx.x >> 6;
    if (lane == 0) wsum[w] = s;
    __syncthreads();
    if (threadIdx.x == 0) inv[0] = 1.f / (sqrtf(wsum[0]+wsum[1]+wsum[2]+wsum[3]) + EPS_F);
}

// X (f32, 1M elems) -> bf16
__global__ void kxbf(const float* __restrict__ X, short* __restrict__ Xb) {
    int i = blockIdx.x*blockDim.x + threadIdx.x;    // group of 8
    const float4* p = (const float4*)(X + (size_t)i*8);
    float4 v0 = p[0], v1 = p[1];
    *(ull*)&Xb[(size_t)i*8    ] = pack4(v0.x, v0.y, v0.z, v0.w);
    *(ull*)&Xb[(size_t)i*8 + 4] = pack4(v1.x, v1.y, v1.z, v1.w);
}

// ---------------- split-K GEMM, r5 schedule at 512 threads (max occupancy) ----------
// C_part[split][128][8192] = Ab[128][K](bf16) * op(B),
//   op(B)[k][n] = TRANSB ? Qg[n][k] : Qg[k][n]
// BM=128, BN=64, BK=32, 8 waves (4m x 2n quadrants), split-K=8, non-atomic partials.
// Loop: LOAD(next tile -> regs); MFMA(buf cur); WRITE(buf nxt); __syncthreads.
template<bool TRANSB>
__global__ __launch_bounds__(512) void gemm_w(
    const short* __restrict__ Ab, const float* __restrict__ Qg,
    float* __restrict__ Cp, int N, int K, int KC)
{
    constexpr int LDT = 40;                 // shorts/row: 32 data + 8 pad (80 B)
    constexpr int ASZ = 128 * LDT;
    constexpr int BSZ = 64 * LDT;
    __shared__ short As[2][ASZ];
    __shared__ short Bs[2][BSZ];

    const int t    = threadIdx.x;
    const int lane = t & 63;
    const int w    = t >> 6;                // 0..7
    const int wm   = (w >> 1) * 32;         // 0/32/64/96
    const int wn   = (w & 1)  * 32;         // 0/32
    const int l16  = lane & 15;
    const int lq   = lane >> 4;
    const int n0   = blockIdx.x * 64;
    const int kb   = blockIdx.y * KC;
    const int NS   = KC >> 5;

    float* Cout = Cp + (size_t)blockIdx.y * (128 * 8192);

    // staging decomposition (512 threads)
    const int ar0 = t >> 2, ako = (t & 3) * 8;      // A: one short8/thread (128 x 32)
    const int br0 = t >> 3, bko = (t & 7) * 4;      // B copy: one float4/thread (64 x 32)
    const int bn  = t & 63, bkq = t >> 6;           // B transpose: col bn, row-quad bkq (4 rows)

    f32x4 acc[2][2];
    #pragma unroll
    for (int i = 0; i < 2; ++i) { acc[i][0] = (f32x4){0,0,0,0}; acc[i][1] = (f32x4){0,0,0,0}; }

    short8 sa;                  // staged A regs
    float4 sb;                  // staged B regs (copy path)
    float  sbt[4];              // staged B regs (transpose path)

#define LOAD_T(k0) do {                                                           \
        sa = *(const short8*)&Ab[(size_t)ar0*K + (k0) + ako];                     \
        if constexpr (TRANSB) {                                                   \
            sb = *(const float4*)&Qg[(size_t)(n0+br0)*K + (k0) + bko];            \
        } else {                                                                  \
            _Pragma("unroll")                                                     \
            for (int j = 0; j < 4; ++j)                                           \
                sbt[j] = Qg[(size_t)((k0) + bkq*4 + j)*N + n0 + bn];              \
        }                                                                         \
    } while (0)

#define WRITE_T(buf) do {                                                         \
        *(short8*)&As[buf][ar0*LDT + ako] = sa;                                   \
        if constexpr (TRANSB) {                                                   \
            *(ull*)&Bs[buf][br0*LDT + bko] = pack4(sb.x, sb.y, sb.z, sb.w);       \
        } else {                                                                  \
            *(ull*)&Bs[buf][bn*LDT + bkq*4] = pack4(sbt[0], sbt[1], sbt[2], sbt[3]); \
        }                                                                         \
    } while (0)

#define MFMA_T(buf) do {                                                          \
        short8 af[2], bfr[2];                                                     \
        _Pragma("unroll")                                                         \
        for (int mt = 0; mt < 2; ++mt)                                            \
            af[mt] = *(const short8*)&As[buf][(wm + mt*16 + l16)*LDT + lq*8];     \
        _Pragma("unroll")                                                         \
        for (int nt = 0; nt < 2; ++nt)                                            \
            bfr[nt] = *(const short8*)&Bs[buf][(wn + nt*16 + l16)*LDT + lq*8];    \
        _Pragma("unroll")                                                         \
        for (int mt = 0; mt < 2; ++mt) {                                          \
            acc[mt][0] = __builtin_amdgcn_mfma_f32_16x16x32_bf16(af[mt], bfr[0], acc[mt][0], 0, 0, 0); \
            acc[mt][1] = __builtin_amdgcn_mfma_f32_16x16x32_bf16(af[mt], bfr[1], acc[mt][1], 0, 0, 0); \
        }                                                                         \
    } while (0)

    // ---- prologue: tile 0
    LOAD_T(kb);
    WRITE_T(0);
    __syncthreads();

    for (int ks = 0; ks < NS; ++ks) {
        const int cur = ks & 1;
        const bool more = (ks + 1 < NS);
        if (more) LOAD_T(kb + (ks + 1) * 32);
        MFMA_T(cur);
        if (more) WRITE_T(cur ^ 1);
        __syncthreads();
    }

#undef LOAD_T
#undef WRITE_T
#undef MFMA_T

    // ---- epilogue: non-atomic partial store
    #pragma unroll
    for (int mt = 0; mt < 2; ++mt)
        #pragma unroll
        for (int nt = 0; nt < 2; ++nt)
            #pragma unroll
            for (int r = 0; r < 4; ++r)
                Cout[(size_t)(wm + mt*16 + lq*4 + r)*N + n0 + wn + nt*16 + l16] = acc[mt][nt][r];
}

// ---------------- fused Horner (reduces GEMM1 partials, emits bf16 R k-major) ---------
__global__ __launch_bounds__(512) void horner_fused(
    const float* __restrict__ FF, const float* __restrict__ invn,
    const float* __restrict__ lam, const float* __restrict__ gam,
    const float* __restrict__ Yp, short* __restrict__ Rg, int N)
{
    constexpr int LDT = 136;
    constexpr int T = 14;
    constexpr int SPL = 8;
    __shared__ short Abf[128 * LDT];        // [m][k]
    __shared__ short Rs[32 * LDT];          // [j_local][m]

    const int t    = threadIdx.x;
    const int lane = t & 63;
    const int w    = t >> 6;
    const int wm   = (w >> 1) * 32;
    const int wn   = (w & 1) * 16;
    const int l16  = lane & 15;
    const int lq   = lane >> 4;
    const int j0   = blockIdx.x * 32;

    #pragma unroll
    for (int i = 0; i < 8; ++i) {
        int flat = t + i*512;
        int m = flat >> 5, k4 = flat & 31;
        float4 v = *(const float4*)&FF[m*128 + k4*4];
        *(ull*)&Abf[m*LDT + k4*4] = pack4(v.x, v.y, v.z, v.w);
    }
    {
        int j = t & 31, mg = t >> 5;
        float vv[8];
        #pragma unroll
        for (int r2 = 0; r2 < 8; ++r2) {
            size_t idx = (size_t)(mg*8 + r2)*N + j0 + j;
            float s = 0.f;
            #pragma unroll
            for (int sp = 0; sp < SPL; ++sp) s += Yp[(size_t)sp*(128*8192) + idx];
            vv[r2] = s;
        }
        *(ull*)&Rs[j*LDT + mg*8    ] = pack4(vv[0], vv[1], vv[2], vv[3]);
        *(ull*)&Rs[j*LDT + mg*8 + 4] = pack4(vv[4], vv[5], vv[6], vv[7]);
    }
    __syncthreads();

    const int col = j0 + wn + l16;
    float yreg[2][4];
    #pragma unroll
    for (int mt = 0; mt < 2; ++mt)
        #pragma unroll
        for (int r = 0; r < 4; ++r)
            yreg[mt][r] = bf2f((unsigned short)Rs[(wn + l16)*LDT + wm + mt*16 + lq*4 + r]);
    const float s = gam[0] * lam[col] * invn[0];

    for (int it = 0; it < T; ++it) {
        f32x4 racc[2];
        racc[0] = (f32x4){0,0,0,0};
        racc[1] = (f32x4){0,0,0,0};
        #pragma unroll
        for (int kq = 0; kq < 4; ++kq) {
            short8 b  = *(const short8*)&Rs[(wn + l16)*LDT + kq*32 + lq*8];
            short8 a0 = *(const short8*)&Abf[(wm      + l16)*LDT + kq*32 + lq*8];
            short8 a1 = *(const short8*)&Abf[(wm + 16 + l16)*LDT + kq*32 + lq*8];
            racc[0] = __builtin_amdgcn_mfma_f32_16x16x32_bf16(a0, b, racc[0], 0, 0, 0);
            racc[1] = __builtin_amdgcn_mfma_f32_16x16x32_bf16(a1, b, racc[1], 0, 0, 0);
        }
        __syncthreads();
        #pragma unroll
        for (int mt = 0; mt < 2; ++mt) {
            float r0 = yreg[mt][0] + s*racc[mt][0];
            float r1 = yreg[mt][1] + s*racc[mt][1];
            float r2 = yreg[mt][2] + s*racc[mt][2];
            float r3 = yreg[mt][3] + s*racc[mt][3];
            if (it < T-1) {
                *(ull*)&Rs[(wn + l16)*LDT + wm + mt*16 + lq*4] = pack4(r0, r1, r2, r3);
            } else {
                int row = wm + mt*16 + lq*4;
                Rg[(size_t)(row+0)*N + col] = (short)f2bf(r0);
                Rg[(size_t)(row+1)*N + col] = (short)f2bf(r1);
                Rg[(size_t)(row+2)*N + col] = (short)f2bf(r2);
                Rg[(size_t)(row+3)*N + col] = (short)f2bf(r3);
            }
        }
        if (it < T-1) __syncthreads();
    }
}

// ---------------- Z = sum of 8 split partials ----------------
__global__ __launch_bounds__(256) void zred(const float* __restrict__ Zp,
                                            float* __restrict__ Z) {
    int i = (blockIdx.x*blockDim.x + threadIdx.x) * 4;
    f32x4 s = (f32x4){0,0,0,0};
    #pragma unroll
    for (int sp = 0; sp < 8; ++sp) {
        const float4 v = *(const float4*)&Zp[(size_t)sp*(128*8192) + i];
        s[0] += v.x; s[1] += v.y; s[2] += v.z; s[3] += v.w;
    }
    *(f32x4*)&Z[i] = s;
}

// ---------------- launch ----------------

extern "C" void kernel_launch(void* const* d_in, const int* in_sizes, int n_in,
                              void* d_out, int out_size, void* d_ws, size_t ws_size,
                              hipStream_t stream) {
    const float* X   = (const float*)d_in[0];   // 128 x 8192
    const float* F   = (const float*)d_in[1];   // 128 x 128
    const float* Q   = (const float*)d_in[2];   // 8192 x 8192
    const float* lam = (const float*)d_in[3];   // 8192
    const float* gam = (const float*)d_in[4];   // 1
    float* Z = (float*)d_out;                   // 128 x 8192 (f32)

    const int N = 8192, K = 8192;

    char* ws = (char*)d_ws;
    float* FF  = (float*)(ws);                               // 64 KB
    float* inv = (float*)(ws + 65536);                       // 4 B
    short* Xb  = (short*)(ws + 131072);                      // 2 MB
    short* Rg  = (short*)(ws + 2228224);                     // 2 MB
    float* Yp  = (float*)(ws + 4325376);                     // 8 x 4 MB
    float* Zp  = (float*)(ws + 4325376 + 33554432);          // 8 x 4 MB

    hipLaunchKernelGGL(kff,   dim3(128), dim3(128), 0, stream, F, FF);
    hipLaunchKernelGGL(knorm, dim3(1),   dim3(256), 0, stream, FF, inv);
    hipLaunchKernelGGL(kxbf,  dim3(512), dim3(256), 0, stream, X, Xb);

    // GEMM1: Yp[s] = Xb @ Q   (512-thr r5 schedule, split-K=8, all blocks resident)
    hipLaunchKernelGGL((gemm_w<false>), dim3(128, 8), dim3(512), 0, stream,
                       Xb, Q, Yp, N, K, 1024);

    // fused Horner: reduce 8 partials, Neumann series, emit bf16 R (k-major)
    hipLaunchKernelGGL(horner_fused, dim3(256), dim3(512), 0, stream,
                       FF, inv, lam, gam, Yp, Rg, N);

    // GEMM2: Zp[s] = Rg @ Q^T  (512-thr, split-K=8)
    hipLaunchKernelGGL((gemm_w<true>), dim3(128, 8), dim3(512), 0, stream,
                       Rg, Q, Zp, N, K, 1024);

    // Z = sum_s Zp[s]
    hipLaunchKernelGGL(zred, dim3(1024), dim3(256), 0, stream, Zp, Z);
}